// Round 6
// baseline (298.026 us; speedup 1.0000x reference)
//
#include <hip/hip_runtime.h>
#include <math.h>

// Problem constants (from reference setup_inputs)
#define T_TOKENS 16384
#define DIM      2048
#define NEXP     64
#define TOPK     2

// Flat fp32 output layout: combine | topk_idx | gates | expert_activation
#define OFF_COMBINE 0
#define OFF_IDX     (T_TOKENS * NEXP)
#define OFF_GATES   (OFF_IDX + T_TOKENS * TOPK)
#define OFF_ACT     (OFF_GATES + T_TOKENS * TOPK)

#define WT_PLANE (NEXP * DIM)   // one bf16 plane of transposed w, in elements

#define GRP   16                // tokens per block (one MFMA row-tile)
#define NKC   4                 // K-split waves per block
#define KC    (DIM / NKC)       // 512 k per wave
#define NSTEP (KC / 32)         // 16 K-steps of 32

typedef __attribute__((ext_vector_type(8))) short  short8;   // 8 bf16 in 4 VGPRs
typedef __attribute__((ext_vector_type(4))) float  f32x4;

#define MFMA16(a, b, c) __builtin_amdgcn_mfma_f32_16x16x32_bf16((a), (b), (c), 0, 0, 0)

// Static device storage: 3 bf16 planes (h,m,l) of wt[e][k] = 768 KB.
__device__ __align__(16) unsigned short g_wt[3 * WT_PLANE];

// ---------------------------------------------------------------------------
// Setup: transpose w [DIM][NEXP] -> wt[e][k], 3-way bf16 TRUNCATION split.
// h = top16(v); r1 = v-h exact; m = top16(r1); l = top16(r1-m).
// Coalesced 16B writes per thread. Also zeroes expert_activation.
// ---------------------------------------------------------------------------
__global__ void wsplit_kernel(const float* __restrict__ w,
                              float* __restrict__ out) {
    const int tid = threadIdx.x;           // 0..255
    const int e   = blockIdx.x;            // 0..63
    if (e == 0 && tid < NEXP) out[OFF_ACT + tid] = 0.0f;

    const int k0 = tid * 8;
    short8 hs, ms, ls;
    #pragma unroll
    for (int i = 0; i < 8; ++i) {
        const float v = w[(size_t)(k0 + i) * NEXP + e];
        const unsigned int bv = __builtin_bit_cast(unsigned int, v);
        const unsigned int hb = bv & 0xFFFF0000u;
        const float r1 = v - __builtin_bit_cast(float, hb);
        const unsigned int r1b = __builtin_bit_cast(unsigned int, r1);
        const unsigned int mb = r1b & 0xFFFF0000u;
        const float r2 = r1 - __builtin_bit_cast(float, mb);
        const unsigned int lb = __builtin_bit_cast(unsigned int, r2);
        hs[i] = (short)(hb >> 16);
        ms[i] = (short)(mb >> 16);
        ls[i] = (short)(lb >> 16);
    }
    *reinterpret_cast<short8*>(&g_wt[(size_t)e * DIM + k0])                = hs;
    *reinterpret_cast<short8*>(&g_wt[(size_t)e * DIM + k0 + WT_PLANE])     = ms;
    *reinterpret_cast<short8*>(&g_wt[(size_t)e * DIM + k0 + 2 * WT_PLANE]) = ls;
}

// fp32x8 -> bf16 truncation split (ah, am, al)
__device__ __forceinline__ void split8(const float4 a, const float4 b,
                                       short8& ah, short8& am, short8& al) {
    float v[8] = {a.x, a.y, a.z, a.w, b.x, b.y, b.z, b.w};
    #pragma unroll
    for (int i = 0; i < 8; ++i) {
        const unsigned int bv = __builtin_bit_cast(unsigned int, v[i]);
        const unsigned int hb = bv & 0xFFFF0000u;
        const float r1 = v[i] - __builtin_bit_cast(float, hb);
        const unsigned int r1b = __builtin_bit_cast(unsigned int, r1);
        const unsigned int mb = r1b & 0xFFFF0000u;
        const float r2 = r1 - __builtin_bit_cast(float, mb);
        const unsigned int lb = __builtin_bit_cast(unsigned int, r2);
        ah[i] = (short)(hb >> 16);
        am[i] = (short)(mb >> 16);
        al[i] = (short)(lb >> 16);
    }
}

// ---------------------------------------------------------------------------
// Router v6 — max-TLP, zero main-loop machinery.
// Wave = 16 tokens x 64 experts x 512 k (K-split 4). Block = 256 thr = the
// 4 K-split waves of one token group. Grid 1024 = 4 blocks/CU = 16 waves/CU
// (2x v5 — the only lever that has moved this kernel: 4w/CU=166us,
// 8w/CU=108-115us across four structures). Direct global->register loads,
// no LDS staging, no barriers in the K-loop; per step a wave issues 12 W
// short8 loads (L2) + depth-1 A prefetch (HBM) back-to-back (~14KB MLP),
// then 24 MFMA. Latency hides across 4 waves/SIMD (m114 TLP).
// ---------------------------------------------------------------------------
__global__ __launch_bounds__(256, 4)
void router_kernel(const float* __restrict__ x,
                   const float* __restrict__ noise,
                   float* __restrict__ out) {
    __shared__ float part[NKC][GRP][68];   // 17.4 KB K-split partials
    __shared__ float nsh[GRP][68];         // 4.4 KB staged noise
    __shared__ float g1s[GRP], g2s[GRP];
    __shared__ int   i1s[GRP], i2s[GRP];
    __shared__ float bins[NEXP];

    const int tid  = threadIdx.x;
    const int l    = tid & 63;
    const int kc   = tid >> 6;        // wave id = K chunk (uniform per wave)
    const int lrow = l & 15;          // MFMA fragment row/col
    const int lk   = l >> 4;          // k-subgroup (0..3) * 8
    const int brow = blockIdx.x * GRP;

    if (tid < NEXP) bins[tid] = 0.0f;

    // Stage noise rows (16 x 64 f32 = 256 float4 over 256 threads).
    {
        const int r = tid >> 4, c = (tid & 15) * 4;
        *reinterpret_cast<float4*>(&nsh[r][c]) =
            *reinterpret_cast<const float4*>(noise + (size_t)(brow + r) * NEXP + c);
    }

    // A: lane reads x[brow + lrow][kc*512 + s*32 + lk*8 .. +8]
    const float* xa = x + (size_t)(brow + lrow) * DIM + kc * KC + lk * 8;
    // W: lane reads wt[n*16 + lrow][kc*512 + s*32 + lk*8 .. +8] per plane
    const unsigned short* wb0 = g_wt + (size_t)(0 * 16 + lrow) * DIM + kc * KC + lk * 8;
    const unsigned short* wb1 = g_wt + (size_t)(1 * 16 + lrow) * DIM + kc * KC + lk * 8;
    const unsigned short* wb2 = g_wt + (size_t)(2 * 16 + lrow) * DIM + kc * KC + lk * 8;
    const unsigned short* wb3 = g_wt + (size_t)(3 * 16 + lrow) * DIM + kc * KC + lk * 8;

    f32x4 acc[4];
    #pragma unroll
    for (int n = 0; n < 4; ++n) acc[n] = (f32x4){0.f, 0.f, 0.f, 0.f};

    // Depth-1 A prefetch (HBM ~900cy hides under one full step).
    float4 A0 = *reinterpret_cast<const float4*>(xa);
    float4 A1 = *reinterpret_cast<const float4*>(xa + 4);

    #pragma unroll 1
    for (int s = 0; s < NSTEP; ++s) {
        const int sn = (s + 1 < NSTEP) ? (s + 1) : s;   // tail: harmless reload
        const float4 N0 = *reinterpret_cast<const float4*>(xa + sn * 32);
        const float4 N1 = *reinterpret_cast<const float4*>(xa + sn * 32 + 4);

        // 12 W-fragment loads, issued back-to-back (L2-resident g_wt).
        const int so = s * 32;
        const short8 Wh0 = *reinterpret_cast<const short8*>(wb0 + so);
        const short8 Wm0 = *reinterpret_cast<const short8*>(wb0 + so + WT_PLANE);
        const short8 Wl0 = *reinterpret_cast<const short8*>(wb0 + so + 2 * WT_PLANE);
        const short8 Wh1 = *reinterpret_cast<const short8*>(wb1 + so);
        const short8 Wm1 = *reinterpret_cast<const short8*>(wb1 + so + WT_PLANE);
        const short8 Wl1 = *reinterpret_cast<const short8*>(wb1 + so + 2 * WT_PLANE);
        const short8 Wh2 = *reinterpret_cast<const short8*>(wb2 + so);
        const short8 Wm2 = *reinterpret_cast<const short8*>(wb2 + so + WT_PLANE);
        const short8 Wl2 = *reinterpret_cast<const short8*>(wb2 + so + 2 * WT_PLANE);
        const short8 Wh3 = *reinterpret_cast<const short8*>(wb3 + so);
        const short8 Wm3 = *reinterpret_cast<const short8*>(wb3 + so + WT_PLANE);
        const short8 Wl3 = *reinterpret_cast<const short8*>(wb3 + so + 2 * WT_PLANE);

        // Split current A while the W loads fly (no dependency).
        short8 ah, am, al;
        split8(A0, A1, ah, am, al);

        // 6 split-products per e-frag: h*h + h*m + m*h + h*l + m*m + l*h
        acc[0] = MFMA16(ah, Wh0, acc[0]);
        acc[0] = MFMA16(ah, Wm0, acc[0]);
        acc[0] = MFMA16(am, Wh0, acc[0]);
        acc[0] = MFMA16(ah, Wl0, acc[0]);
        acc[0] = MFMA16(am, Wm0, acc[0]);
        acc[0] = MFMA16(al, Wh0, acc[0]);
        acc[1] = MFMA16(ah, Wh1, acc[1]);
        acc[1] = MFMA16(ah, Wm1, acc[1]);
        acc[1] = MFMA16(am, Wh1, acc[1]);
        acc[1] = MFMA16(ah, Wl1, acc[1]);
        acc[1] = MFMA16(am, Wm1, acc[1]);
        acc[1] = MFMA16(al, Wh1, acc[1]);
        acc[2] = MFMA16(ah, Wh2, acc[2]);
        acc[2] = MFMA16(ah, Wm2, acc[2]);
        acc[2] = MFMA16(am, Wh2, acc[2]);
        acc[2] = MFMA16(ah, Wl2, acc[2]);
        acc[2] = MFMA16(am, Wm2, acc[2]);
        acc[2] = MFMA16(al, Wh2, acc[2]);
        acc[3] = MFMA16(ah, Wh3, acc[3]);
        acc[3] = MFMA16(ah, Wm3, acc[3]);
        acc[3] = MFMA16(am, Wh3, acc[3]);
        acc[3] = MFMA16(ah, Wl3, acc[3]);
        acc[3] = MFMA16(am, Wm3, acc[3]);
        acc[3] = MFMA16(al, Wh3, acc[3]);

        A0 = N0; A1 = N1;
    }

    // C/D layout (m89-verified): col = lane&15 (expert), row = (lane>>4)*4+reg (token).
    #pragma unroll
    for (int n = 0; n < 4; ++n)
        #pragma unroll
        for (int j = 0; j < 4; ++j)
            part[kc][lk * 4 + j][n * 16 + lrow] = acc[n][j];
    __syncthreads();

    // Epilogue: threads 0..15, one token row each. Sum K-partials, noise, top-2.
    if (tid < GRP) {
        const int r   = tid;
        const int row = brow + r;
        float m1 = -1e30f, m2 = -1e30f;
        int i1 = 0, i2 = 0;
        #pragma unroll
        for (int j = 0; j < NEXP; j += 4) {
            float4 s4       = *reinterpret_cast<const float4*>(&part[0][r][j]);
            const float4 p1 = *reinterpret_cast<const float4*>(&part[1][r][j]);
            const float4 p2 = *reinterpret_cast<const float4*>(&part[2][r][j]);
            const float4 p3 = *reinterpret_cast<const float4*>(&part[3][r][j]);
            const float4 nv = *reinterpret_cast<const float4*>(&nsh[r][j]);
            s4.x += p1.x + p2.x + p3.x + nv.x;
            s4.y += p1.y + p2.y + p3.y + nv.y;
            s4.z += p1.z + p2.z + p3.z + nv.z;
            s4.w += p1.w + p2.w + p3.w + nv.w;
            if (s4.x > m1) { m2 = m1; i2 = i1; m1 = s4.x; i1 = j + 0; } else if (s4.x > m2) { m2 = s4.x; i2 = j + 0; }
            if (s4.y > m1) { m2 = m1; i2 = i1; m1 = s4.y; i1 = j + 1; } else if (s4.y > m2) { m2 = s4.y; i2 = j + 1; }
            if (s4.z > m1) { m2 = m1; i2 = i1; m1 = s4.z; i1 = j + 2; } else if (s4.z > m2) { m2 = s4.z; i2 = j + 2; }
            if (s4.w > m1) { m2 = m1; i2 = i1; m1 = s4.w; i1 = j + 3; } else if (s4.w > m2) { m2 = s4.w; i2 = j + 3; }
        }

        // Softmax Z cancels under top-2 renorm: g1 = 1/(1+exp(l2-l1)).
        const float t  = expf(m2 - m1);
        const float g1 = 1.0f / (1.0f + t);
        const float g2 = 1.0f - g1;

        out[OFF_IDX + row * 2 + 0]   = (float)i1;
        out[OFF_IDX + row * 2 + 1]   = (float)i2;
        out[OFF_GATES + row * 2 + 0] = g1;
        out[OFF_GATES + row * 2 + 1] = g2;

        g1s[r] = g1; g2s[r] = g2; i1s[r] = i1; i2s[r] = i2;
        atomicAdd(&bins[i1], 1.0f);
        atomicAdd(&bins[i2], 1.0f);
    }
    __syncthreads();

    // Combine tile write: 16 x 64 f32 = 256 float4 over 256 threads.
    {
        const int r = tid >> 4, c = (tid & 15) * 4;
        const int   a  = i1s[r], b = i2s[r];
        const float ga = g1s[r], gb = g2s[r];
        float4 v;
        v.x = (c + 0 == a) ? ga : (c + 0 == b) ? gb : 0.0f;
        v.y = (c + 1 == a) ? ga : (c + 1 == b) ? gb : 0.0f;
        v.z = (c + 2 == a) ? ga : (c + 2 == b) ? gb : 0.0f;
        v.w = (c + 3 == a) ? ga : (c + 3 == b) ? gb : 0.0f;
        *reinterpret_cast<float4*>(
            out + OFF_COMBINE + (size_t)(brow + r) * NEXP + c) = v;
    }

    if (tid < NEXP) {
        const float v = bins[tid];
        if (v != 0.0f) atomicAdd(out + OFF_ACT + tid, v);
    }
}

extern "C" void kernel_launch(void* const* d_in, const int* in_sizes, int n_in,
                              void* d_out, int out_size, void* d_ws, size_t ws_size,
                              hipStream_t stream) {
    const float* x     = (const float*)d_in[0];
    const float* wg    = (const float*)d_in[1];
    const float* noise = (const float*)d_in[2];
    float* out = (float*)d_out;

    wsplit_kernel<<<NEXP, 256, 0, stream>>>(wg, out);
    router_kernel<<<T_TOKENS / GRP, 256, 0, stream>>>(x, noise, out);
}

// Round 7
// 228.490 us; speedup vs baseline: 1.3043x; 1.3043x over previous
//
#include <hip/hip_runtime.h>
#include <math.h>

// Problem constants (from reference setup_inputs)
#define T_TOKENS 16384
#define DIM      2048
#define NEXP     64
#define TOPK     2

// Flat fp32 output layout: combine | topk_idx | gates | expert_activation
#define OFF_COMBINE 0
#define OFF_IDX     (T_TOKENS * NEXP)
#define OFF_GATES   (OFF_IDX + T_TOKENS * TOPK)
#define OFF_ACT     (OFF_GATES + T_TOKENS * TOPK)

#define CHUNKS 8
#define CK     256                       // k's per K-chunk
#define CSTEPS (CK / 32)                 // 8 MFMA K-steps per tile
#define PLANE_SHORTS (NEXP * CK)         // 16384 shorts per plane per chunk
#define WCH_SHORTS   (3 * PLANE_SHORTS)  // 49152 shorts = 96 KB per chunk

// Pass-1 LDS partition (bytes): A = 4 waves x 16 KB, W = 96 KB. Total 160 KB.
#define LDS_A_WAVE 16384
#define LDS_W_BASE 65536
#define LDS_TOTAL  163840

typedef __attribute__((ext_vector_type(8))) short  short8;   // 8 bf16 in 4 VGPRs
typedef __attribute__((ext_vector_type(4))) float  f32x4;

#define MFMA16(a, b, c) __builtin_amdgcn_mfma_f32_16x16x32_bf16((a), (b), (c), 0, 0, 0)

// Static device storage.
__device__ __align__(16) unsigned short g_wt3[CHUNKS * WCH_SHORTS];   // 768 KB split W
__device__ __align__(16) float g_part[CHUNKS * T_TOKENS * NEXP];      // 32 MB partials

// ---------------------------------------------------------------------------
// Setup: w [DIM][NEXP] -> wt3 [chunk][plane][e][k%CK] bf16 truncation split
// (h = top16(v), m = top16(v-h), l = top16(v-h-m); exact fp32 residuals).
// Per-chunk-contiguous layout makes pass-1 W staging fully coalesced.
// Also zeroes expert_activation.
// ---------------------------------------------------------------------------
__global__ void wsplit_kernel(const float* __restrict__ w,
                              float* __restrict__ out) {
    const int tid = threadIdx.x;           // 0..255
    const int e   = blockIdx.x;            // 0..63
    if (e == 0 && tid < NEXP) out[OFF_ACT + tid] = 0.0f;

    const int k0    = tid * 8;
    const int chunk = k0 >> 8;
    const int kin   = k0 & 255;
    short8 hs, ms, ls;
    #pragma unroll
    for (int i = 0; i < 8; ++i) {
        const float v = w[(size_t)(k0 + i) * NEXP + e];
        const unsigned int bv = __builtin_bit_cast(unsigned int, v);
        const unsigned int hb = bv & 0xFFFF0000u;
        const float r1 = v - __builtin_bit_cast(float, hb);
        const unsigned int r1b = __builtin_bit_cast(unsigned int, r1);
        const unsigned int mb = r1b & 0xFFFF0000u;
        const float r2 = r1 - __builtin_bit_cast(float, mb);
        const unsigned int lb = __builtin_bit_cast(unsigned int, r2);
        hs[i] = (short)(hb >> 16);
        ms[i] = (short)(mb >> 16);
        ls[i] = (short)(lb >> 16);
    }
    unsigned short* dst = g_wt3 + (size_t)chunk * WCH_SHORTS + e * CK + kin;
    *reinterpret_cast<short8*>(dst)                    = hs;
    *reinterpret_cast<short8*>(dst + PLANE_SHORTS)     = ms;
    *reinterpret_cast<short8*>(dst + 2 * PLANE_SHORTS) = ls;
}

__device__ __forceinline__ void gload_lds16(const void* g, void* s) {
    __builtin_amdgcn_global_load_lds(
        (const __attribute__((address_space(1))) void*)g,
        (__attribute__((address_space(3))) void*)s, 16, 0, 0);
}

// fp32x8 -> bf16 truncation split (ah, am, al)
__device__ __forceinline__ void split8(const float4 a, const float4 b,
                                       short8& ah, short8& am, short8& al) {
    float v[8] = {a.x, a.y, a.z, a.w, b.x, b.y, b.z, b.w};
    #pragma unroll
    for (int i = 0; i < 8; ++i) {
        const unsigned int bv = __builtin_bit_cast(unsigned int, v[i]);
        const unsigned int hb = bv & 0xFFFF0000u;
        const float r1 = v[i] - __builtin_bit_cast(float, hb);
        const unsigned int r1b = __builtin_bit_cast(unsigned int, r1);
        const unsigned int mb = r1b & 0xFFFF0000u;
        const float r2 = r1 - __builtin_bit_cast(float, mb);
        const unsigned int lb = __builtin_bit_cast(unsigned int, r2);
        ah[i] = (short)(hb >> 16);
        am[i] = (short)(mb >> 16);
        al[i] = (short)(lb >> 16);
    }
}

// ---------------------------------------------------------------------------
// Pass 1: partial scores. Grid 256 = 8 K-chunks x 32 token-groups
// (chunk = blockIdx&7 -> same-chunk blocks share an XCD's L2 for W).
// Block = 256 thr = 4 waves, 1 block/CU (160 KB LDS).
//   - W chunk (96 KB, 3 planes x 64e x 256k bf16) staged ONCE per block via
//     coalesced 16B loads + XOR-swizzled ds_write. Reused by 512 tokens —
//     the W-reuse that was 1x in all previous rounds.
//   - Per wave, 8 tiles of 16 tokens: A staged via 16 global_load_lds ops,
//     each ONE CONTIGUOUS 1KB row (1-2 L1 transactions vs 32 for the
//     scattered per-lane fragment loads of v0-v6), source pre-XOR-swizzled,
//     wave-private -> vmcnt(0) only, NO barriers in the K-loop.
//   - 8 steps x {2 A + 12 W swizzled ds_read_b128 (verified minimum 8
//     bank-touches) + split + 24 MFMA}; partials stored to g_part.
// ---------------------------------------------------------------------------
__global__ __launch_bounds__(256, 1)
void score_kernel(const float* __restrict__ x) {
    __shared__ __align__(16) unsigned char lds[LDS_TOTAL];

    const int tid  = threadIdx.x;
    const int l    = tid & 63;
    const int wv   = __builtin_amdgcn_readfirstlane(tid >> 6);  // 0..3
    const int lrow = l & 15;
    const int lk   = l >> 4;          // 0..3
    const int chunk = blockIdx.x & 7;
    const int tg    = blockIdx.x >> 3;      // 0..31
    const int tok0  = tg * 512;

    // ---- stage W chunk: 6144 16B-slots, 24 rounds, swizzled ds_write ----
    {
        const unsigned short* src = g_wt3 + (size_t)chunk * WCH_SHORTS;
        #pragma unroll 4
        for (int r = 0; r < 24; ++r) {
            const int idx = tid + r * 256;        // global slot id
            const short8 v = *reinterpret_cast<const short8*>(src + idx * 8);
            const int p   = idx >> 11;            // plane
            const int rem = idx & 2047;
            const int e   = rem >> 5;
            const int s   = rem & 31;
            *reinterpret_cast<short8*>(
                lds + LDS_W_BASE + p * 32768 + e * 512 + ((s ^ (e & 7)) * 16)) = v;
        }
    }
    __syncthreads();   // W visible to all waves; no barriers after this

    unsigned char* aw = lds + wv * LDS_A_WAVE;   // wave-private A tile

    #pragma unroll 1
    for (int ti = 0; ti < 8; ++ti) {
        const int tile0 = tok0 + (wv * 8 + ti) * 16;

        // Stage A: 16 rows x 1KB contiguous; source pre-swizzled so LDS slot
        // sl of row o holds global 16B-chunk sl ^ (o&7).
        #pragma unroll
        for (int o = 0; o < 16; ++o) {
            const float* src = x + (size_t)(tile0 + o) * DIM + chunk * CK
                                 + ((l ^ (o & 7)) << 2);
            gload_lds16(src, aw + o * 1024);
        }
        asm volatile("s_waitcnt vmcnt(0)" ::: "memory");
        __builtin_amdgcn_sched_barrier(0);

        f32x4 acc[4];
        #pragma unroll
        for (int n = 0; n < 4; ++n) acc[n] = (f32x4){0.f, 0.f, 0.f, 0.f};

        #pragma unroll
        for (int s = 0; s < CSTEPS; ++s) {
            // A fragment: row lrow, global chunks g = s*8 + 2lk (+1),
            // read LDS slot g ^ (lrow&7).
            const int g0 = s * 8 + 2 * lk;
            const float4 xa0 = *reinterpret_cast<const float4*>(
                aw + lrow * 1024 + ((g0 ^ (lrow & 7)) * 16));
            const float4 xa1 = *reinterpret_cast<const float4*>(
                aw + lrow * 1024 + (((g0 + 1) ^ (lrow & 7)) * 16));
            short8 ah, am, al;
            split8(xa0, xa1, ah, am, al);

            const int ws = s * 4 + lk;   // W slot within e-row (pre-swizzle)
            #pragma unroll
            for (int n = 0; n < 4; ++n) {
                const int e = n * 16 + lrow;
                const unsigned char* wb =
                    lds + LDS_W_BASE + e * 512 + ((ws ^ (e & 7)) * 16);
                const short8 Wh = *reinterpret_cast<const short8*>(wb);
                const short8 Wm = *reinterpret_cast<const short8*>(wb + 32768);
                const short8 Wl = *reinterpret_cast<const short8*>(wb + 65536);
                // 6 split-products: h*h + h*m + m*h + h*l + m*m + l*h
                acc[n] = MFMA16(ah, Wh, acc[n]);
                acc[n] = MFMA16(ah, Wm, acc[n]);
                acc[n] = MFMA16(am, Wh, acc[n]);
                acc[n] = MFMA16(ah, Wl, acc[n]);
                acc[n] = MFMA16(am, Wm, acc[n]);
                acc[n] = MFMA16(al, Wh, acc[n]);
            }
        }

        // Store partials. C/D layout (m89): col=lane&15 (expert),
        // row=(lane>>4)*4+reg (token). Per instr: 4 tokens x 64B contiguous.
        float* pb = g_part + ((size_t)chunk * T_TOKENS + tile0) * NEXP;
        #pragma unroll
        for (int n = 0; n < 4; ++n)
            #pragma unroll
            for (int j = 0; j < 4; ++j)
                pb[(lk * 4 + j) * NEXP + n * 16 + lrow] = acc[n][j];
    }
}

// ---------------------------------------------------------------------------
// Pass 2: reduce 8 partials + noise -> top-2, gates, combine, activations.
// Grid 256, block 256 = 64 tokens. Traffic ~36 MB total.
// ---------------------------------------------------------------------------
__global__ __launch_bounds__(256, 2)
void reduce_kernel(const float* __restrict__ noise,
                   float* __restrict__ out) {
    __shared__ float scores[64][68];
    __shared__ float g1s[64], g2s[64];
    __shared__ int   i1s[64], i2s[64];
    __shared__ float bins[NEXP];

    const int tid  = threadIdx.x;
    const int brow = blockIdx.x * 64;
    const int r    = tid >> 2;        // token row 0..63
    const int q    = tid & 3;         // 16-expert column group

    if (tid < NEXP) bins[tid] = 0.0f;

    // Sum 8 chunk partials + noise for (r, q*16..+16).
    {
        const int c0 = q * 16;
        float4 s0 = *reinterpret_cast<const float4*>(noise + (size_t)(brow + r) * NEXP + c0);
        float4 s1 = *reinterpret_cast<const float4*>(noise + (size_t)(brow + r) * NEXP + c0 + 4);
        float4 s2 = *reinterpret_cast<const float4*>(noise + (size_t)(brow + r) * NEXP + c0 + 8);
        float4 s3 = *reinterpret_cast<const float4*>(noise + (size_t)(brow + r) * NEXP + c0 + 12);
        #pragma unroll
        for (int c = 0; c < CHUNKS; ++c) {
            const float* pb = g_part + ((size_t)c * T_TOKENS + brow + r) * NEXP + c0;
            const float4 p0 = *reinterpret_cast<const float4*>(pb);
            const float4 p1 = *reinterpret_cast<const float4*>(pb + 4);
            const float4 p2 = *reinterpret_cast<const float4*>(pb + 8);
            const float4 p3 = *reinterpret_cast<const float4*>(pb + 12);
            s0.x += p0.x; s0.y += p0.y; s0.z += p0.z; s0.w += p0.w;
            s1.x += p1.x; s1.y += p1.y; s1.z += p1.z; s1.w += p1.w;
            s2.x += p2.x; s2.y += p2.y; s2.z += p2.z; s2.w += p2.w;
            s3.x += p3.x; s3.y += p3.y; s3.z += p3.z; s3.w += p3.w;
        }
        *reinterpret_cast<float4*>(&scores[r][c0])      = s0;
        *reinterpret_cast<float4*>(&scores[r][c0 + 4])  = s1;
        *reinterpret_cast<float4*>(&scores[r][c0 + 8])  = s2;
        *reinterpret_cast<float4*>(&scores[r][c0 + 12]) = s3;
    }
    __syncthreads();

    // Top-2 per token: threads 0..63.
    if (tid < 64) {
        const int row = brow + tid;
        float m1 = -1e30f, m2 = -1e30f;
        int i1 = 0, i2 = 0;
        #pragma unroll
        for (int j = 0; j < NEXP; j += 4) {
            const float4 s4 = *reinterpret_cast<const float4*>(&scores[tid][j]);
            if (s4.x > m1) { m2 = m1; i2 = i1; m1 = s4.x; i1 = j + 0; } else if (s4.x > m2) { m2 = s4.x; i2 = j + 0; }
            if (s4.y > m1) { m2 = m1; i2 = i1; m1 = s4.y; i1 = j + 1; } else if (s4.y > m2) { m2 = s4.y; i2 = j + 1; }
            if (s4.z > m1) { m2 = m1; i2 = i1; m1 = s4.z; i1 = j + 2; } else if (s4.z > m2) { m2 = s4.z; i2 = j + 2; }
            if (s4.w > m1) { m2 = m1; i2 = i1; m1 = s4.w; i1 = j + 3; } else if (s4.w > m2) { m2 = s4.w; i2 = j + 3; }
        }

        // Softmax Z cancels under top-2 renorm: g1 = 1/(1+exp(l2-l1)).
        const float t  = expf(m2 - m1);
        const float g1 = 1.0f / (1.0f + t);
        const float g2 = 1.0f - g1;

        out[OFF_IDX + row * 2 + 0]   = (float)i1;
        out[OFF_IDX + row * 2 + 1]   = (float)i2;
        out[OFF_GATES + row * 2 + 0] = g1;
        out[OFF_GATES + row * 2 + 1] = g2;

        g1s[tid] = g1; g2s[tid] = g2; i1s[tid] = i1; i2s[tid] = i2;
        atomicAdd(&bins[i1], 1.0f);
        atomicAdd(&bins[i2], 1.0f);
    }
    __syncthreads();

    // Combine tile write: 64 x 64 f32 = 1024 float4 over 256 thr x 4.
    #pragma unroll
    for (int i = 0; i < 4; ++i) {
        const int idx = tid + i * 256;
        const int rr = idx >> 4, c = (idx & 15) * 4;
        const int   a  = i1s[rr], b = i2s[rr];
        const float ga = g1s[rr], gb = g2s[rr];
        float4 v;
        v.x = (c + 0 == a) ? ga : (c + 0 == b) ? gb : 0.0f;
        v.y = (c + 1 == a) ? ga : (c + 1 == b) ? gb : 0.0f;
        v.z = (c + 2 == a) ? ga : (c + 2 == b) ? gb : 0.0f;
        v.w = (c + 3 == a) ? ga : (c + 3 == b) ? gb : 0.0f;
        *reinterpret_cast<float4*>(
            out + OFF_COMBINE + (size_t)(brow + rr) * NEXP + c) = v;
    }

    if (tid < NEXP) {
        const float v = bins[tid];
        if (v != 0.0f) atomicAdd(out + OFF_ACT + tid, v);
    }
}

extern "C" void kernel_launch(void* const* d_in, const int* in_sizes, int n_in,
                              void* d_out, int out_size, void* d_ws, size_t ws_size,
                              hipStream_t stream) {
    const float* x     = (const float*)d_in[0];
    const float* wg    = (const float*)d_in[1];
    const float* noise = (const float*)d_in[2];
    float* out = (float*)d_out;

    wsplit_kernel<<<NEXP, 256, 0, stream>>>(wg, out);
    score_kernel<<<CHUNKS * 32, 256, 0, stream>>>(x);
    reduce_kernel<<<T_TOKENS / 64, 256, 0, stream>>>(noise, out);
}

// Round 8
// 221.557 us; speedup vs baseline: 1.3451x; 1.0313x over previous
//
#include <hip/hip_runtime.h>
#include <math.h>

// Problem constants (from reference setup_inputs)
#define T_TOKENS 16384
#define DIM      2048
#define NEXP     64
#define TOPK     2

// Flat fp32 output layout: combine | topk_idx | gates | expert_activation
#define OFF_COMBINE 0
#define OFF_IDX     (T_TOKENS * NEXP)
#define OFF_GATES   (OFF_IDX + T_TOKENS * TOPK)
#define OFF_ACT     (OFF_GATES + T_TOKENS * TOPK)

#define BK      64                       // k's per K-iteration
#define NITER   (DIM / BK)               // 32
#define WCH_SH  (3 * NEXP * BK)          // 12288 shorts per K-chunk (3 planes)

// LDS ring (bytes): A dbuf 2x16K, W dbuf 2x24K = 80 KB exactly.
#define A_BUF_B 16384
#define W_BASE  32768
#define W_BUF_B 24576
#define LDS_B   81920

typedef __attribute__((ext_vector_type(8))) short  short8;   // 8 bf16 in 4 VGPRs
typedef __attribute__((ext_vector_type(4))) float  f32x4;

#define MFMA16(a, b, c) __builtin_amdgcn_mfma_f32_16x16x32_bf16((a), (b), (c), 0, 0, 0)

// Split W, chunk-major: [chunk32][plane3][e64][kin64] bf16 = 768 KB.
__device__ __align__(16) unsigned short g_wt3[NITER * WCH_SH];

// ---------------------------------------------------------------------------
// Setup: w [DIM][NEXP] -> g_wt3, 3-way bf16 TRUNCATION split
// (h = top16(v), m = top16(v-h), l = top16(v-h-m); exact fp32 residuals).
// Chunk-major layout makes every router W-stage op 1KB-contiguous.
// Also zeroes expert_activation.
// ---------------------------------------------------------------------------
__global__ void wsplit_kernel(const float* __restrict__ w,
                              float* __restrict__ out) {
    const int tid = threadIdx.x;           // 0..255
    const int e   = blockIdx.x;            // 0..63
    if (e == 0 && tid < NEXP) out[OFF_ACT + tid] = 0.0f;

    const int k0    = tid * 8;
    const int chunk = tid >> 3;            // k0/64
    const int kin   = (tid & 7) * 8;
    short8 hs, ms, ls;
    #pragma unroll
    for (int i = 0; i < 8; ++i) {
        const float v = w[(size_t)(k0 + i) * NEXP + e];
        const unsigned int bv = __builtin_bit_cast(unsigned int, v);
        const unsigned int hb = bv & 0xFFFF0000u;
        const float r1 = v - __builtin_bit_cast(float, hb);
        const unsigned int r1b = __builtin_bit_cast(unsigned int, r1);
        const unsigned int mb = r1b & 0xFFFF0000u;
        const float r2 = r1 - __builtin_bit_cast(float, mb);
        const unsigned int lb = __builtin_bit_cast(unsigned int, r2);
        hs[i] = (short)(hb >> 16);
        ms[i] = (short)(mb >> 16);
        ls[i] = (short)(lb >> 16);
    }
    unsigned short* dst = g_wt3 + (size_t)chunk * WCH_SH + e * BK + kin;
    *reinterpret_cast<short8*>(dst)            = hs;
    *reinterpret_cast<short8*>(dst + NEXP*BK)  = ms;
    *reinterpret_cast<short8*>(dst + 2*NEXP*BK)= ls;
}

__device__ __forceinline__ void gload_lds16(const void* g, void* s) {
    __builtin_amdgcn_global_load_lds(
        (const __attribute__((address_space(1))) void*)g,
        (__attribute__((address_space(3))) void*)s, 16, 0, 0);
}

// fp32x8 -> bf16 truncation split (ah, am, al)
__device__ __forceinline__ void split8(const float4 a, const float4 b,
                                       short8& ah, short8& am, short8& al) {
    float v[8] = {a.x, a.y, a.z, a.w, b.x, b.y, b.z, b.w};
    #pragma unroll
    for (int i = 0; i < 8; ++i) {
        const unsigned int bv = __builtin_bit_cast(unsigned int, v[i]);
        const unsigned int hb = bv & 0xFFFF0000u;
        const float r1 = v[i] - __builtin_bit_cast(float, hb);
        const unsigned int r1b = __builtin_bit_cast(unsigned int, r1);
        const unsigned int mb = r1b & 0xFFFF0000u;
        const float r2 = r1 - __builtin_bit_cast(float, mb);
        const unsigned int lb = __builtin_bit_cast(unsigned int, r2);
        ah[i] = (short)(hb >> 16);
        am[i] = (short)(mb >> 16);
        al[i] = (short)(lb >> 16);
    }
}

// ---------------------------------------------------------------------------
// Router v8 — fused single-pass, m97 2-phase template.
// Grid 256 = 1 block/CU. Block = 512 thr = 8 waves = 2/SIMD (the occupancy
// v7 lacked). Tile: 64 tokens x 64 experts x full K. Wave (mt = wv>>1,
// nh = wv&1) owns tokens mt*16..+16, experts nh*32..+32 (2 e-frags).
// Per iter (BK=64): stage next A (16KB, 16 x 1KB-contiguous gload_lds) +
// W chunk (24KB, 24 x 1KB-contiguous) into the 80KB double-buffered ring,
// compute 2 MFMA-steps (24 MFMA, 16 swizzled ds_read_b128, 1 split8),
// __syncthreads (compiler vmcnt-drain = the ring swap fence).
// XOR-swizzled LDS (pre-swizzled gload source + swizzled read; <=2-way
// bank conflicts, verified by hand). Scores never leave the block:
// epilogue (noise/top-2/gates/combine/bins) runs on ring-aliased LDS.
// No g_part, no reduce pass.
// ---------------------------------------------------------------------------
__global__ __launch_bounds__(512, 1)
void router_kernel(const float* __restrict__ x,
                   const float* __restrict__ noise,
                   float* __restrict__ out) {
    __shared__ __align__(16) unsigned char lds[LDS_B];

    const int tid  = threadIdx.x;
    const int l    = tid & 63;
    const int wv   = __builtin_amdgcn_readfirstlane(tid >> 6);  // 0..7
    const int lrow = l & 15;
    const int lk   = l >> 4;          // 0..3
    const int mt   = wv >> 1;         // token sub-tile
    const int nh   = wv & 1;          // expert half
    const int brow = blockIdx.x * 64;

    // ---- staging addresses (pre-swizzled source, linear LDS dest) -------
    // A: 16 ops of 1KB = 4 rows x 256B. op = wv*2+t. lane l -> row
    // ro = op*4 + (l>>4), LDS slot l&15; slot sl of row ro holds global
    // 16B-chunk sl ^ (ro&15).
    const float* asrc[2];
    int adst[2];
    #pragma unroll
    for (int t = 0; t < 2; ++t) {
        const int op = wv * 2 + t;
        const int ro = op * 4 + (l >> 4);
        asrc[t] = x + (size_t)(brow + ro) * DIM + (((l & 15) ^ (ro & 15)) << 2);
        adst[t] = op * 1024;
    }
    // W: 24 ops of 1KB = 8 e-rows x 128B. op w = wv*3+t; p = w>>3, q = w&7;
    // lane l -> e = q*8 + (l>>3), LDS slot l&7; slot sl holds chunk sl^(e&7).
    const unsigned short* wsrc[3];
    int wdst[3];
    #pragma unroll
    for (int t = 0; t < 3; ++t) {
        const int w = wv * 3 + t;
        const int p = w >> 3, q = w & 7;
        const int e = q * 8 + (l >> 3);
        wsrc[t] = g_wt3 + p * (NEXP * BK) + e * BK + (((l & 7) ^ (e & 7)) << 3);
        wdst[t] = W_BASE + p * 8192 + q * 1024;
    }

#define STAGE(bf, it) do {                                                    \
        gload_lds16(asrc[0] + (it) * BK, lds + (bf) * A_BUF_B + adst[0]);     \
        gload_lds16(asrc[1] + (it) * BK, lds + (bf) * A_BUF_B + adst[1]);     \
        gload_lds16(wsrc[0] + (size_t)(it) * WCH_SH, lds + (bf) * W_BUF_B + wdst[0]); \
        gload_lds16(wsrc[1] + (size_t)(it) * WCH_SH, lds + (bf) * W_BUF_B + wdst[1]); \
        gload_lds16(wsrc[2] + (size_t)(it) * WCH_SH, lds + (bf) * W_BUF_B + wdst[2]); \
    } while (0)

    // ---- fragment read addresses ----------------------------------------
    const int arow = mt * 16 + lrow;                 // A row (token)
    const int e0   = (nh * 2 + 0) * 16 + lrow;       // e-frag 0 row
    const int e1   = (nh * 2 + 1) * 16 + lrow;       // e-frag 1 row

    f32x4 acc[2];
    acc[0] = (f32x4){0.f, 0.f, 0.f, 0.f};
    acc[1] = acc[0];

    STAGE(0, 0);
    __syncthreads();

    #pragma unroll 2
    for (int it = 0; it < NITER; ++it) {
        const int b  = it & 1;
        const int tn = (it + 1 < NITER) ? (it + 1) : it;   // tail: harmless restage
        STAGE(b ^ 1, tn);   // in flight across this iter's compute

        const unsigned char* ab = lds + b * A_BUF_B + arow * 256;
        const unsigned char* w0 = lds + b * W_BUF_B + W_BASE + e0 * 128;
        const unsigned char* w1 = lds + b * W_BUF_B + W_BASE + e1 * 128;

        #pragma unroll
        for (int s = 0; s < 2; ++s) {
            const int g0 = s * 8 + 2 * lk;
            const float4 xa0 = *reinterpret_cast<const float4*>(
                ab + (((g0)     ^ (arow & 15)) << 4));
            const float4 xa1 = *reinterpret_cast<const float4*>(
                ab + (((g0 + 1) ^ (arow & 15)) << 4));
            short8 ah, am, al;
            split8(xa0, xa1, ah, am, al);

            const int ws = s * 4 + lk;
            const int o0 = ((ws ^ (e0 & 7)) << 4);
            const int o1 = ((ws ^ (e1 & 7)) << 4);
            const short8 Wh0 = *reinterpret_cast<const short8*>(w0 + o0);
            const short8 Wm0 = *reinterpret_cast<const short8*>(w0 + 8192 + o0);
            const short8 Wl0 = *reinterpret_cast<const short8*>(w0 + 16384 + o0);
            const short8 Wh1 = *reinterpret_cast<const short8*>(w1 + o1);
            const short8 Wm1 = *reinterpret_cast<const short8*>(w1 + 8192 + o1);
            const short8 Wl1 = *reinterpret_cast<const short8*>(w1 + 16384 + o1);

            // 6 split-products: h*h + h*m + m*h + h*l + m*m + l*h
            acc[0] = MFMA16(ah, Wh0, acc[0]);
            acc[0] = MFMA16(ah, Wm0, acc[0]);
            acc[0] = MFMA16(am, Wh0, acc[0]);
            acc[0] = MFMA16(ah, Wl0, acc[0]);
            acc[0] = MFMA16(am, Wm0, acc[0]);
            acc[0] = MFMA16(al, Wh0, acc[0]);
            acc[1] = MFMA16(ah, Wh1, acc[1]);
            acc[1] = MFMA16(ah, Wm1, acc[1]);
            acc[1] = MFMA16(am, Wh1, acc[1]);
            acc[1] = MFMA16(ah, Wl1, acc[1]);
            acc[1] = MFMA16(am, Wm1, acc[1]);
            acc[1] = MFMA16(al, Wh1, acc[1]);
        }
        __syncthreads();   // vmcnt drain: next buf landed, this buf's reads done
    }
#undef STAGE

    // ---- epilogue on ring-aliased LDS ------------------------------------
    float (*scores)[68] = reinterpret_cast<float (*)[68]>(lds);            // 17408 B
    float (*nsh)[68]    = reinterpret_cast<float (*)[68]>(lds + 17408);    // 17408 B
    float* g1s  = reinterpret_cast<float*>(lds + 34816);
    float* g2s  = g1s + 64;
    int*   i1s  = reinterpret_cast<int*>(g2s + 64);
    int*   i2s  = i1s + 64;
    float* bins = reinterpret_cast<float*>(i2s + 64);

    // C/D layout (m89-verified): col = lane&15 (expert), row = (lane>>4)*4+reg.
    #pragma unroll
    for (int n = 0; n < 2; ++n)
        #pragma unroll
        for (int j = 0; j < 4; ++j)
            scores[mt * 16 + lk * 4 + j][(nh * 2 + n) * 16 + lrow] = acc[n][j];

    if (tid < NEXP) bins[tid] = 0.0f;

    // Stage noise rows (64 x 64 f32 = 1024 float4 over 512 thr x 2), coalesced.
    #pragma unroll
    for (int i = 0; i < 2; ++i) {
        const int idx = tid + i * 512;
        const int r = idx >> 4, c = (idx & 15) * 4;
        *reinterpret_cast<float4*>(&nsh[r][c]) =
            *reinterpret_cast<const float4*>(noise + (size_t)(brow + r) * NEXP + c);
    }
    __syncthreads();

    // Top-2 per token: threads 0..63.
    if (tid < 64) {
        const int r   = tid;
        const int row = brow + r;
        float m1 = -1e30f, m2 = -1e30f;
        int i1 = 0, i2 = 0;
        #pragma unroll
        for (int j = 0; j < NEXP; j += 4) {
            float4 s4       = *reinterpret_cast<const float4*>(&scores[r][j]);
            const float4 nv = *reinterpret_cast<const float4*>(&nsh[r][j]);
            s4.x += nv.x; s4.y += nv.y; s4.z += nv.z; s4.w += nv.w;
            if (s4.x > m1) { m2 = m1; i2 = i1; m1 = s4.x; i1 = j + 0; } else if (s4.x > m2) { m2 = s4.x; i2 = j + 0; }
            if (s4.y > m1) { m2 = m1; i2 = i1; m1 = s4.y; i1 = j + 1; } else if (s4.y > m2) { m2 = s4.y; i2 = j + 1; }
            if (s4.z > m1) { m2 = m1; i2 = i1; m1 = s4.z; i1 = j + 2; } else if (s4.z > m2) { m2 = s4.z; i2 = j + 2; }
            if (s4.w > m1) { m2 = m1; i2 = i1; m1 = s4.w; i1 = j + 3; } else if (s4.w > m2) { m2 = s4.w; i2 = j + 3; }
        }

        // Softmax Z cancels under top-2 renorm: g1 = 1/(1+exp(l2-l1)).
        const float t  = expf(m2 - m1);
        const float g1 = 1.0f / (1.0f + t);
        const float g2 = 1.0f - g1;

        out[OFF_IDX + row * 2 + 0]   = (float)i1;
        out[OFF_IDX + row * 2 + 1]   = (float)i2;
        out[OFF_GATES + row * 2 + 0] = g1;
        out[OFF_GATES + row * 2 + 1] = g2;

        g1s[r] = g1; g2s[r] = g2; i1s[r] = i1; i2s[r] = i2;
        atomicAdd(&bins[i1], 1.0f);
        atomicAdd(&bins[i2], 1.0f);
    }
    __syncthreads();

    // Combine tile write: 64 x 64 f32 = 1024 float4 over 512 thr x 2.
    #pragma unroll
    for (int i = 0; i < 2; ++i) {
        const int idx = tid + i * 512;
        const int r = idx >> 4, c = (idx & 15) * 4;
        const int   a  = i1s[r], b = i2s[r];
        const float ga = g1s[r], gb = g2s[r];
        float4 v;
        v.x = (c + 0 == a) ? ga : (c + 0 == b) ? gb : 0.0f;
        v.y = (c + 1 == a) ? ga : (c + 1 == b) ? gb : 0.0f;
        v.z = (c + 2 == a) ? ga : (c + 2 == b) ? gb : 0.0f;
        v.w = (c + 3 == a) ? ga : (c + 3 == b) ? gb : 0.0f;
        *reinterpret_cast<float4*>(
            out + OFF_COMBINE + (size_t)(brow + r) * NEXP + c) = v;
    }

    if (tid < NEXP) {
        const float v = bins[tid];
        if (v != 0.0f) atomicAdd(out + OFF_ACT + tid, v);
    }
}

extern "C" void kernel_launch(void* const* d_in, const int* in_sizes, int n_in,
                              void* d_out, int out_size, void* d_ws, size_t ws_size,
                              hipStream_t stream) {
    const float* x     = (const float*)d_in[0];
    const float* wg    = (const float*)d_in[1];
    const float* noise = (const float*)d_in[2];
    float* out = (float*)d_out;

    wsplit_kernel<<<NEXP, 256, 0, stream>>>(wg, out);
    router_kernel<<<T_TOKENS / 64, 512, 0, stream>>>(x, noise, out);
}